// Round 14
// baseline (952.998 us; speedup 1.0000x reference)
//
#include <hip/hip_runtime.h>
#include <hip/hip_bf16.h>

#define BB 8192
#define SS 20
#define DD 300
#define JJ 512
#define NII 1000
#define VGG 2078
#define BP1 72           // k1 64x64 chunk lds row stride

typedef __attribute__((ext_vector_type(8))) short short8v;
typedef __attribute__((ext_vector_type(4))) float float4v;

__device__ __forceinline__ unsigned short bf16u(float x) {
    __hip_bfloat16 h = __float2bfloat16(x);
    return *(unsigned short*)&h;
}
// async global->LDS, 16B per lane; LDS dest = wave-uniform base + lane*16
__device__ __forceinline__ void gload16(const void* g, void* l) {
    __builtin_amdgcn_global_load_lds(
        (const __attribute__((address_space(1))) unsigned int*)g,
        (__attribute__((address_space(3))) unsigned int*)l, 16, 0, 0);
}

// ---------------- combined pad+convert for W_emb (512 rows) + guide (1000 rows) -
__global__ __launch_bounds__(256) void kc_pad2(const float* __restrict__ W_emb,
                                               const float* __restrict__ guide,
                                               __hip_bfloat16* __restrict__ Web,
                                               __hip_bfloat16* __restrict__ Gb) {
    long idx = (long)blockIdx.x * 256 + threadIdx.x;
    if (idx >= 1512L * 2112) return;
    int r = (int)(idx / 2112), c = (int)(idx % 2112);
    if (r < JJ) {
        float v = (c < VGG) ? W_emb[(long)r * VGG + c] : 0.f;
        Web[(long)r * 2112 + c] = __float2bfloat16(v);
    } else {
        int g = r - JJ;
        float v = (c < VGG) ? guide[(long)g * VGG + c] : 0.f;
        Gb[(long)g * 2112 + c] = __float2bfloat16(v);
    }
}

// ---------------- Wsb2 prep: pre-swizzled [2 jhalf][256 r][320 c] --------------
// element (jh,r,c): blk=c>>3 e=c&7; source col = ((blk ^ (r&7))<<3)|e of
// W'[j=jh*256+r], W' = [W_sent row | b_sent | b_emb | 0...]. Linear
// global_load_lds then yields LDS[r][blk] = W'[j][blk^(r&7)]; reader XORs back.
// Verified conflict-free (rounds 9/10: SQ_LDS_BANK_CONFLICT = 0) and correct.
__global__ __launch_bounds__(256) void kc_prep_wsb2(const float* __restrict__ W_sent,
                                                    const float* __restrict__ b_sent,
                                                    const float* __restrict__ b_emb,
                                                    __hip_bfloat16* __restrict__ dst) {
    int idx = blockIdx.x * 256 + threadIdx.x;
    if (idx >= 2 * 256 * 320) return;
    int jh = idx / (256 * 320);
    int rem = idx - jh * (256 * 320);
    int r = rem / 320, c = rem - (rem / 320) * 320;
    int blk = c >> 3, e = c & 7;
    int sc = ((blk ^ (r & 7)) << 3) | e;
    int j = jh * 256 + r;
    float v = (sc < DD) ? W_sent[(long)j * DD + sc]
            : (sc == DD) ? b_sent[j]
            : (sc == DD + 1) ? b_emb[j] : 0.f;
    dst[idx] = __float2bfloat16(v);
}

// ---------------- sum of w_fc (one block) --------------------------------------
__global__ __launch_bounds__(512) void kS_sumwf(const float* __restrict__ w_fc,
                                                float* __restrict__ out) {
    __shared__ float part[8];
    int t = threadIdx.x;
    float v = w_fc[t];
    v += __shfl_xor(v, 1);  v += __shfl_xor(v, 2);  v += __shfl_xor(v, 4);
    v += __shfl_xor(v, 8);  v += __shfl_xor(v, 16); v += __shfl_xor(v, 32);
    if ((t & 63) == 0) part[t >> 6] = v;
    __syncthreads();
    if (t == 0) {
        float s = 0.f;
#pragma unroll
        for (int i = 0; i < 8; ++i) s += part[i];
        out[0] = s;
    }
}

// ---------------- kernel 0: valid / nonzero masks + scores init ---------------
__global__ __launch_bounds__(256) void k0_valid(const int* __restrict__ labels,
                                                const float* __restrict__ sums,
                                                const float* __restrict__ b_fc,
                                                float* __restrict__ valid,
                                                float* __restrict__ nonzero,
                                                float* __restrict__ scores) {
    int b = blockIdx.x * blockDim.x + threadIdx.x;
    if (b >= BB) return;
    float v = 1.f;
    float init = b_fc[0] + sums[0];
    for (int s = 0; s < SS; ++s) {
        float nz = (labels[b * SS + s] != 0) ? 1.f : 0.f;
        v *= nz;
        nonzero[b * SS + s] = nz;
        valid[b * SS + s] = v;
        scores[b * SS + s] = init;
    }
}

// ---------------- kernel 1 (MFMA): femb = bf16(guide @ W_emb^T + b_emb) --------
__global__ __launch_bounds__(256) void k1_femb_mfma(
    const __hip_bfloat16* __restrict__ Gb,   // [NII][2112]
    const __hip_bfloat16* __restrict__ Web,  // [JJ][2112]
    const float* __restrict__ b_emb,
    __hip_bfloat16* __restrict__ femb) {     // [1024][JJ]
    __shared__ __hip_bfloat16 Al[64 * BP1];
    __shared__ __hip_bfloat16 Bl[64 * BP1];
    const int t = threadIdx.x;
    const int m0 = blockIdx.x * 64;
    const int n0 = blockIdx.y * 64;
    const int lane = t & 63;
    const int w = t >> 6;
    const int wm = w >> 1, wn = w & 1;
    const int li = lane & 15, lq = lane >> 4;

    float4v acc[2][2] = {};

    for (int kt = 0; kt < 33; ++kt) {
        for (int c = t; c < 512; c += 256) {
            int rr = c >> 3, off = (c & 7) * 8;
            int gr = m0 + rr; if (gr > NII - 1) gr = NII - 1;
            *(uint4*)&Al[rr * BP1 + off] =
                *(const uint4*)(Gb + (long)gr * 2112 + kt * 64 + off);
            *(uint4*)&Bl[rr * BP1 + off] =
                *(const uint4*)(Web + (long)(n0 + rr) * 2112 + kt * 64 + off);
        }
        __syncthreads();
#pragma unroll
        for (int ks = 0; ks < 2; ++ks) {
            short8v a[2], b[2];
#pragma unroll
            for (int mt = 0; mt < 2; ++mt)
                a[mt] = *(const short8v*)&Al[(wm * 32 + mt * 16 + li) * BP1 + ks * 32 + lq * 8];
#pragma unroll
            for (int nt = 0; nt < 2; ++nt)
                b[nt] = *(const short8v*)&Bl[(wn * 32 + nt * 16 + li) * BP1 + ks * 32 + lq * 8];
#pragma unroll
            for (int mt = 0; mt < 2; ++mt)
#pragma unroll
                for (int nt = 0; nt < 2; ++nt)
                    acc[mt][nt] = __builtin_amdgcn_mfma_f32_16x16x32_bf16(
                        a[mt], b[nt], acc[mt][nt], 0, 0, 0);
        }
        __syncthreads();
    }
#pragma unroll
    for (int nt = 0; nt < 2; ++nt) {
        int col = n0 + wn * 32 + nt * 16 + li;
        float be = b_emb[col];
#pragma unroll
        for (int mt = 0; mt < 2; ++mt)
#pragma unroll
            for (int reg = 0; reg < 4; ++reg) {
                int row = wm * 32 + mt * 16 + lq * 4 + reg;
                femb[(long)(m0 + row) * JJ + col] = __float2bfloat16(acc[mt][nt][reg] + be);
            }
    }
}

// ---------------- kernel 2 (MFMA): persistent-B fused scores ------------------
// 512 threads (8 waves), grid 128 m-chunks x 2 j-halves, 1 block/CU (160KB LDS).
// B j-half (256x320 bf16 = 160KB) staged ONCE via global_load_lds from the
// pre-swizzled Wsb2; ONE barrier total; LDS read-only afterwards -> waves run
// free over 10 m-tiles of 128 rows (wave: 16 rows). A from global f32 in regs
// (bias cols folded at k300/301). Zero-LDS designs are L2-BW-capped (every
// wave reads 320KB -> 3.35GB L2 = 97us floor); this reads B once per block.
// amdgpu_waves_per_eu(2,4): unlock VGPR budget (proven at 256 thr, round 12);
// round 9's 1024-thread version got heuristic-capped at 64 VGPR and spilled.
__global__ __launch_bounds__(512)
__attribute__((amdgpu_waves_per_eu(2, 4)))
void k2_scores_mfma(
    const float* __restrict__ context,
    const __hip_bfloat16* __restrict__ Wsb2, // pre-swizzled [2][256][320]
    const float* __restrict__ w_fc,
    const __hip_bfloat16* __restrict__ femb, // [1024][JJ]
    const int* __restrict__ ann,
    const float* __restrict__ valid,
    float* __restrict__ scores) {
    extern __shared__ __align__(16) char smem[];   // 163840 B
    const int t = threadIdx.x;
    const int wid = t >> 6, lane = t & 63;
    const int li = lane & 15, lq = lane >> 4;
    const int jh = blockIdx.y;
    const int rowbase = blockIdx.x * 1280;

    // ---- stage B half once (10240 x 16B chunks, linear; 20 per lane) ----
    {
        const char* g = (const char*)Wsb2 + (long)jh * 163840;
        const int base = wid * 1280;
#pragma unroll
        for (int i = 0; i < 20; ++i)
            gload16(g + (long)(base + i * 64 + lane) * 16,
                    smem + (base + i * 64) * 16);
    }
    // ---- w_fc preload (jh-constant) as packed bf16 pairs ----
    unsigned wpk[8];
#pragma unroll
    for (int n = 0; n < 8; ++n) {
        wpk[n] = ((unsigned)bf16u(w_fc[jh * 256 + (2 * n + 1) * 16 + li]) << 16)
               | bf16u(w_fc[jh * 256 + (2 * n) * 16 + li]);
    }
    __syncthreads();   // drains vmcnt; ONLY barrier in the kernel

    const int xorb = (li & 7) << 4;    // byte-XOR for swizzled read
    const int lqb  = lq << 4;
    const unsigned short* fp = (const unsigned short*)femb;

    for (int it = 0; it < 10; ++it) {
        const int m0 = rowbase + it * 128 + wid * 16;
        // ---- A fragments (row = li), f32 -> bf16 in regs ----
        const float* crow = context + (long)(m0 + li) * DD;
        const float vA = valid[m0 + li];
        short8v areg[10];
#pragma unroll
        for (int kt = 0; kt < 9; ++kt) {
            const int k0 = kt * 32 + lq * 8;
            float4 u = *(const float4*)(crow + k0);
            float4 v2 = *(const float4*)(crow + k0 + 4);
            short8v a;
            a[0] = (short)bf16u(u.x);  a[1] = (short)bf16u(u.y);
            a[2] = (short)bf16u(u.z);  a[3] = (short)bf16u(u.w);
            a[4] = (short)bf16u(v2.x); a[5] = (short)bf16u(v2.y);
            a[6] = (short)bf16u(v2.z); a[7] = (short)bf16u(v2.w);
            areg[kt] = a;
        }
        {   // kt=9: k 288..319 with folded bias cols 300 (=1.0) and 301 (=1-valid)
            short8v a = {0, 0, 0, 0, 0, 0, 0, 0};
            if (lq == 0) {
                float4 u = *(const float4*)(crow + 288);
                float4 v2 = *(const float4*)(crow + 292);
                a[0] = (short)bf16u(u.x);  a[1] = (short)bf16u(u.y);
                a[2] = (short)bf16u(u.z);  a[3] = (short)bf16u(u.w);
                a[4] = (short)bf16u(v2.x); a[5] = (short)bf16u(v2.y);
                a[6] = (short)bf16u(v2.z); a[7] = (short)bf16u(v2.w);
            } else if (lq == 1) {
                float4 u = *(const float4*)(crow + 296);
                a[0] = (short)bf16u(u.x);  a[1] = (short)bf16u(u.y);
                a[2] = (short)bf16u(u.z);  a[3] = (short)bf16u(u.w);
                a[4] = (short)bf16u(1.f);  a[5] = (short)bf16u(1.f - vA);
            }
            areg[9] = a;
        }
        // ---- C-row metadata (rows = lq*4+reg) ----
        const int mslot = m0 + lq * 4;
        const int b0 = mslot / SS;
        const int b3 = (mslot + 3) / SS;
        const int g0 = ann[2 * b0];
        const int g1 = ann[2 * b3];
        float vmc[4]; unsigned selm[4];
#pragma unroll
        for (int reg = 0; reg < 4; ++reg) {
            vmc[reg] = valid[mslot + reg];
            selm[reg] = (((mslot + reg) / SS) != b0) ? 0xffffffffu : 0u;
        }
        // femb for both candidate b rows, packed lo=g0 hi=g1
        unsigned fpk[16];
#pragma unroll
        for (int n = 0; n < 16; ++n) {
            const int col = jh * 256 + n * 16 + li;
            unsigned lo = fp[(long)g0 * JJ + col];
            unsigned hi = fp[(long)g1 * JJ + col];
            fpk[n] = (hi << 16) | lo;
        }
        float sp[4] = {0.f, 0.f, 0.f, 0.f};

        // ---- n-loop: pairs for MFMA ILP; epilogue folded immediately ----
#pragma unroll
        for (int np = 0; np < 8; ++np) {
            const char* p0 = smem + (np * 32 + li) * 640;
            const char* p1 = p0 + 16 * 640;
            float4v a0 = {0.f, 0.f, 0.f, 0.f}, a1 = {0.f, 0.f, 0.f, 0.f};
#pragma unroll
            for (int kt = 0; kt < 10; ++kt) {
                const int off = (((kt * 4) << 4) + lqb) ^ xorb;
                short8v b0v = *(const short8v*)(p0 + off);
                short8v b1v = *(const short8v*)(p1 + off);
                a0 = __builtin_amdgcn_mfma_f32_16x16x32_bf16(areg[kt], b0v, a0, 0, 0, 0);
                a1 = __builtin_amdgcn_mfma_f32_16x16x32_bf16(areg[kt], b1v, a1, 0, 0, 0);
            }
            const float wfA = __uint_as_float(wpk[np] << 16);
            const float wfB = __uint_as_float(wpk[np] & 0xffff0000u);
#pragma unroll
            for (int h = 0; h < 2; ++h) {
                const int n = np * 2 + h;
                const unsigned u = fpk[n];
                const unsigned flo = u << 16;
                const unsigned fhi = u & 0xffff0000u;
                const float wfn = (h == 0) ? wfA : wfB;
#pragma unroll
                for (int reg = 0; reg < 4; ++reg) {
                    const float fv = __uint_as_float((flo & ~selm[reg]) | (fhi & selm[reg]));
                    const float ac = (h == 0) ? a0[reg] : a1[reg];
                    const float x = fmaf(vmc[reg], fv, ac);
                    const float e = __expf(x + x);
                    const float r = __builtin_amdgcn_rcpf(e + 1.f);
                    sp[reg] = fmaf(wfn, r, sp[reg]);
                }
            }
        }
        // ---- reduce over the 16 li lanes, atomicAdd partial ----
#pragma unroll
        for (int reg = 0; reg < 4; ++reg) {
            float v = sp[reg];
            v += __shfl_xor(v, 1); v += __shfl_xor(v, 2);
            v += __shfl_xor(v, 4); v += __shfl_xor(v, 8);
            if (li == 0) atomicAdd(&scores[mslot + reg], -2.f * v);
        }
    }
}

// ---------------- kernel 3: softmax + mask + renorm + weighted sum -------------
__global__ __launch_bounds__(256) void k3_out(const float* __restrict__ scores,
                                              const float* __restrict__ nonzero,
                                              const float* __restrict__ embedded,
                                              float* __restrict__ out) {
    __shared__ float wgt[3][SS];
    const int b0 = blockIdx.x * 3;
    const int t = threadIdx.x;
    if (t < 3) {
        int b = b0 + t;
        if (b < BB) {
            float sc[SS], nz[SS];
            float mx = -1e30f;
            for (int s = 0; s < SS; ++s) {
                sc[s] = scores[b * SS + s];
                nz[s] = nonzero[b * SS + s];
                mx = fmaxf(mx, sc[s]);
            }
            float den = 0.f, e[SS];
            for (int s = 0; s < SS; ++s) { e[s] = nz[s] * __expf(sc[s] - mx); den += e[s]; }
            float inv = 1.f / den;
            for (int s = 0; s < SS; ++s) wgt[t][s] = e[s] * inv;
        }
    }
    __syncthreads();
    if (t < 225) {
        int r = t / 75, q = t - r * 75;
        int b = b0 + r;
        if (b < BB) {
            float4 a; a.x = a.y = a.z = a.w = 0.f;
#pragma unroll
            for (int s = 0; s < SS; ++s) {
                float4 e = *(const float4*)(embedded + ((long)b * SS + s) * DD + q * 4);
                float ww = wgt[r][s];
                a.x += ww * e.x; a.y += ww * e.y; a.z += ww * e.z; a.w += ww * e.w;
            }
            *(float4*)(out + (long)b * DD + q * 4) = a;
        }
    }
}

extern "C" void kernel_launch(void* const* d_in, const int* in_sizes, int n_in,
                              void* d_out, int out_size, void* d_ws, size_t ws_size,
                              hipStream_t stream) {
    const float* context  = (const float*)d_in[0];
    const float* embedded = (const float*)d_in[1];
    const int*   labels   = (const int*)d_in[2];
    const float* guide    = (const float*)d_in[3];
    const int*   ann      = (const int*)d_in[4];
    const float* W_sent   = (const float*)d_in[5];
    const float* b_sent   = (const float*)d_in[6];
    const float* W_emb    = (const float*)d_in[7];
    const float* b_emb    = (const float*)d_in[8];
    const float* w_fc     = (const float*)d_in[9];
    const float* b_fc     = (const float*)d_in[10];
    float* out = (float*)d_out;

    char* w = (char*)d_ws;
    __hip_bfloat16* femb = (__hip_bfloat16*)(w);               // 1024*512*2 = 1048576
    float* valid         = (float*)(w + 1048576);              // 655360
    float* nonzero       = (float*)(w + 1703936);              // 655360
    float* scores        = (float*)(w + 2359296);              // 655360
    __hip_bfloat16* Wsb2 = (__hip_bfloat16*)(w + 3014656);     // 2*256*320*2 = 327680
    __hip_bfloat16* Web  = (__hip_bfloat16*)(w + 3342336);     // 512*2112*2  = 2162688
    __hip_bfloat16* Gb   = (__hip_bfloat16*)(w + 5505024);     // 1000*2112*2 = 4224000
    float* sums          = (float*)(w + 9729024);              // 4
    // total 9729028 bytes

    // allow 160KB dynamic LDS for k2 (idempotent host-side call)
    hipFuncSetAttribute((const void*)k2_scores_mfma,
                        hipFuncAttributeMaxDynamicSharedMemorySize, 163840);

    hipLaunchKernelGGL(kc_prep_wsb2, dim3((2 * 256 * 320 + 255) / 256), dim3(256), 0, stream,
                       W_sent, b_sent, b_emb, Wsb2);
    hipLaunchKernelGGL(kc_pad2, dim3((int)((1512L * 2112 + 255) / 256)), dim3(256), 0, stream,
                       W_emb, guide, Web, Gb);
    hipLaunchKernelGGL(kS_sumwf, dim3(1), dim3(512), 0, stream, w_fc, sums);
    hipLaunchKernelGGL(k0_valid, dim3(BB / 256), dim3(256), 0, stream,
                       labels, sums, b_fc, valid, nonzero, scores);
    hipLaunchKernelGGL(k1_femb_mfma, dim3(16, JJ / 64), dim3(256), 0, stream,
                       Gb, Web, b_emb, femb);
    hipLaunchKernelGGL(k2_scores_mfma, dim3(128, 2), dim3(512), 163840, stream,
                       context, Wsb2, w_fc, femb, ann, valid, scores);
    hipLaunchKernelGGL(k3_out, dim3((BB + 2) / 3), dim3(256), 0, stream,
                       scores, nonzero, embedded, out);
}

// Round 15
// 701.207 us; speedup vs baseline: 1.3591x; 1.3591x over previous
//
#include <hip/hip_runtime.h>
#include <hip/hip_bf16.h>

#define BB 8192
#define SS 20
#define DD 300
#define JJ 512
#define NII 1000
#define VGG 2078
#define BP1 72           // k1 64x64 chunk lds row stride

typedef __attribute__((ext_vector_type(8))) short short8v;
typedef __attribute__((ext_vector_type(4))) float float4v;

__device__ __forceinline__ unsigned short bf16u(float x) {
    __hip_bfloat16 h = __float2bfloat16(x);
    return *(unsigned short*)&h;
}

// ---------------- combined pad+convert for W_emb (512 rows) + guide (1000 rows) -
__global__ __launch_bounds__(256) void kc_pad2(const float* __restrict__ W_emb,
                                               const float* __restrict__ guide,
                                               __hip_bfloat16* __restrict__ Web,
                                               __hip_bfloat16* __restrict__ Gb) {
    long idx = (long)blockIdx.x * 256 + threadIdx.x;
    if (idx >= 1512L * 2112) return;
    int r = (int)(idx / 2112), c = (int)(idx % 2112);
    if (r < JJ) {
        float v = (c < VGG) ? W_emb[(long)r * VGG + c] : 0.f;
        Web[(long)r * 2112 + c] = __float2bfloat16(v);
    } else {
        int g = r - JJ;
        float v = (c < VGG) ? guide[(long)g * VGG + c] : 0.f;
        Gb[(long)g * 2112 + c] = __float2bfloat16(v);
    }
}

// ---------------- Wt prep: B-fragment-transposed weights ----------------------
// Wt chunk (kb, col), kb = k/8 in [0,40), col in [0,512): 8 bf16 of
// W'[col][kb*8..kb*8+8), W'[col] = [W_sent row | b_sent | b_emb | 0..].
__global__ __launch_bounds__(256) void kc_prep_wt(const float* __restrict__ W_sent,
                                                  const float* __restrict__ b_sent,
                                                  const float* __restrict__ b_emb,
                                                  __hip_bfloat16* __restrict__ dst) {
    int idx = blockIdx.x * 256 + threadIdx.x;   // chunk id
    if (idx >= 40 * 512) return;
    int kb = idx >> 9, col = idx & 511;
#pragma unroll
    for (int e = 0; e < 8; ++e) {
        int k = kb * 8 + e;
        float v = (k < DD) ? W_sent[(long)col * DD + k]
                : (k == DD) ? b_sent[col]
                : (k == DD + 1) ? b_emb[col] : 0.f;
        dst[(long)idx * 8 + e] = __float2bfloat16(v);
    }
}

// ---------------- sum of w_fc (one block) --------------------------------------
__global__ __launch_bounds__(512) void kS_sumwf(const float* __restrict__ w_fc,
                                                float* __restrict__ out) {
    __shared__ float part[8];
    int t = threadIdx.x;
    float v = w_fc[t];
    v += __shfl_xor(v, 1);  v += __shfl_xor(v, 2);  v += __shfl_xor(v, 4);
    v += __shfl_xor(v, 8);  v += __shfl_xor(v, 16); v += __shfl_xor(v, 32);
    if ((t & 63) == 0) part[t >> 6] = v;
    __syncthreads();
    if (t == 0) {
        float s = 0.f;
#pragma unroll
        for (int i = 0; i < 8; ++i) s += part[i];
        out[0] = s;
    }
}

// ---------------- kernel 0: valid / nonzero masks ----------------
__global__ __launch_bounds__(256) void k0_valid(const int* __restrict__ labels,
                                                float* __restrict__ valid,
                                                float* __restrict__ nonzero) {
    int b = blockIdx.x * blockDim.x + threadIdx.x;
    if (b >= BB) return;
    float v = 1.f;
    for (int s = 0; s < SS; ++s) {
        float nz = (labels[b * SS + s] != 0) ? 1.f : 0.f;
        v *= nz;
        nonzero[b * SS + s] = nz;
        valid[b * SS + s] = v;
    }
}

// ---------------- kernel 1 (MFMA): femb = bf16(guide @ W_emb^T + b_emb) --------
__global__ __launch_bounds__(256) void k1_femb_mfma(
    const __hip_bfloat16* __restrict__ Gb,   // [NII][2112]
    const __hip_bfloat16* __restrict__ Web,  // [JJ][2112]
    const float* __restrict__ b_emb,
    __hip_bfloat16* __restrict__ femb) {     // [1024][JJ]
    __shared__ __hip_bfloat16 Al[64 * BP1];
    __shared__ __hip_bfloat16 Bl[64 * BP1];
    const int t = threadIdx.x;
    const int m0 = blockIdx.x * 64;
    const int n0 = blockIdx.y * 64;
    const int lane = t & 63;
    const int w = t >> 6;
    const int wm = w >> 1, wn = w & 1;
    const int li = lane & 15, lq = lane >> 4;

    float4v acc[2][2] = {};

    for (int kt = 0; kt < 33; ++kt) {
        for (int c = t; c < 512; c += 256) {
            int rr = c >> 3, off = (c & 7) * 8;
            int gr = m0 + rr; if (gr > NII - 1) gr = NII - 1;
            *(uint4*)&Al[rr * BP1 + off] =
                *(const uint4*)(Gb + (long)gr * 2112 + kt * 64 + off);
            *(uint4*)&Bl[rr * BP1 + off] =
                *(const uint4*)(Web + (long)(n0 + rr) * 2112 + kt * 64 + off);
        }
        __syncthreads();
#pragma unroll
        for (int ks = 0; ks < 2; ++ks) {
            short8v a[2], b[2];
#pragma unroll
            for (int mt = 0; mt < 2; ++mt)
                a[mt] = *(const short8v*)&Al[(wm * 32 + mt * 16 + li) * BP1 + ks * 32 + lq * 8];
#pragma unroll
            for (int nt = 0; nt < 2; ++nt)
                b[nt] = *(const short8v*)&Bl[(wn * 32 + nt * 16 + li) * BP1 + ks * 32 + lq * 8];
#pragma unroll
            for (int mt = 0; mt < 2; ++mt)
#pragma unroll
                for (int nt = 0; nt < 2; ++nt)
                    acc[mt][nt] = __builtin_amdgcn_mfma_f32_16x16x32_bf16(
                        a[mt], b[nt], acc[mt][nt], 0, 0, 0);
        }
        __syncthreads();
    }
#pragma unroll
    for (int nt = 0; nt < 2; ++nt) {
        int col = n0 + wn * 32 + nt * 16 + li;
        float be = b_emb[col];
#pragma unroll
        for (int mt = 0; mt < 2; ++mt)
#pragma unroll
            for (int reg = 0; reg < 4; ++reg) {
                int row = wm * 32 + mt * 16 + lq * 4 + reg;
                femb[(long)(m0 + row) * JJ + col] = __float2bfloat16(acc[mt][nt][reg] + be);
            }
    }
}

// ---------------- kernel 2 (MFMA): zero-LDS, 32 rows/wave, pipelined B --------
// 256 threads = 4 waves; each wave owns 32 m-rows (2 m-frags) and sweeps all
// 512 j in 16 np-steps. Every B fragment feeds BOTH m-frags: halves per-output
// L2 B-traffic (3.3GB -> 1.6GB) and gives 4 independent MFMA acc chains (ILP
// for the matrix pipe at 2 waves/SIMD). B 2-deep software pipeline (named
// buffers). waves_per_eu(2,2): pin target at 2 waves/EU -> 256-VGPR cap; the
// (2,4) variant made the allocator spill to chase the 128-reg/4-wave max
// (rounds 13/14: 157MB/285MB scratch).
__global__ __launch_bounds__(256)
__attribute__((amdgpu_waves_per_eu(2, 2)))
void k2_scores_mfma(
    const float* __restrict__ context,
    const __hip_bfloat16* __restrict__ Wt,   // frag-transposed [40*512] chunks
    const float* __restrict__ w_fc,
    const float* __restrict__ b_fc,
    const float* __restrict__ sumwf,
    const __hip_bfloat16* __restrict__ femb, // [1024][JJ]
    const int* __restrict__ ann,
    const float* __restrict__ valid,
    float* __restrict__ scores) {
    const int t = threadIdx.x;
    const int wid = t >> 6, lane = t & 63;
    const int li = lane & 15, lq = lane >> 4;
    const int m0 = blockIdx.x * 128 + wid * 32;

    // ---- A fragments for both m-halves; bias cols folded at k300/301 ----
    short8v areg0[10], areg1[10];
#pragma unroll
    for (int mh = 0; mh < 2; ++mh) {
        const float* crow = context + (long)(m0 + mh * 16 + li) * DD;
        const float vA = valid[m0 + mh * 16 + li];
#pragma unroll
        for (int kt = 0; kt < 9; ++kt) {
            const int k0 = kt * 32 + lq * 8;
            float4 u = *(const float4*)(crow + k0);
            float4 v2 = *(const float4*)(crow + k0 + 4);
            short8v a;
            a[0] = (short)bf16u(u.x);  a[1] = (short)bf16u(u.y);
            a[2] = (short)bf16u(u.z);  a[3] = (short)bf16u(u.w);
            a[4] = (short)bf16u(v2.x); a[5] = (short)bf16u(v2.y);
            a[6] = (short)bf16u(v2.z); a[7] = (short)bf16u(v2.w);
            if (mh == 0) areg0[kt] = a; else areg1[kt] = a;
        }
        short8v a = {0, 0, 0, 0, 0, 0, 0, 0};
        if (lq == 0) {
            float4 u = *(const float4*)(crow + 288);
            float4 v2 = *(const float4*)(crow + 292);
            a[0] = (short)bf16u(u.x);  a[1] = (short)bf16u(u.y);
            a[2] = (short)bf16u(u.z);  a[3] = (short)bf16u(u.w);
            a[4] = (short)bf16u(v2.x); a[5] = (short)bf16u(v2.y);
            a[6] = (short)bf16u(v2.z); a[7] = (short)bf16u(v2.w);
        } else if (lq == 1) {
            float4 u = *(const float4*)(crow + 296);
            a[0] = (short)bf16u(u.x);  a[1] = (short)bf16u(u.y);
            a[2] = (short)bf16u(u.z);  a[3] = (short)bf16u(u.w);
            a[4] = (short)bf16u(1.f);  a[5] = (short)bf16u(1.f - vA);
        }
        if (mh == 0) areg0[9] = a; else areg1[9] = a;
    }

    // ---- C-row metadata for both halves ----
    int g0_[2], g1_[2];
    float vmc[2][4]; unsigned selm[2][4];
#pragma unroll
    for (int mh = 0; mh < 2; ++mh) {
        const int mslot = m0 + mh * 16 + lq * 4;
        const int b0r = mslot / SS;
        g0_[mh] = ann[2 * b0r];
        g1_[mh] = ann[2 * ((mslot + 3) / SS)];
#pragma unroll
        for (int reg = 0; reg < 4; ++reg) {
            vmc[mh][reg] = valid[mslot + reg];
            selm[mh][reg] = (((mslot + reg) / SS) != b0r) ? 0xffffffffu : 0u;
        }
    }
    const unsigned short* fp = (const unsigned short*)femb;
    const __hip_bfloat16* pb = Wt + ((long)lq * 512 + li) * 8;

    float sp[2][4] = {};

    auto loadB = [&](short8v (&buf)[20], int np) {
        const __hip_bfloat16* pn = pb + (long)np * 256;
#pragma unroll
        for (int kt = 0; kt < 10; ++kt) {
            buf[2 * kt]     = *(const short8v*)(pn + (long)kt * 16384);
            buf[2 * kt + 1] = *(const short8v*)(pn + (long)kt * 16384 + 128);
        }
    };
    // 40 MFMA (4 independent chains) + fused epilogue for tile np
    auto computeB = [&](short8v (&buf)[20], int np) {
        const int colA = np * 32 + li;
        const int colB = colA + 16;
        const float wfA = w_fc[colA];
        const float wfB = w_fc[colB];
        unsigned uA[2], uB[2];
#pragma unroll
        for (int mh = 0; mh < 2; ++mh) {
            uA[mh] = ((unsigned)fp[(long)g1_[mh] * JJ + colA] << 16) | fp[(long)g0_[mh] * JJ + colA];
            uB[mh] = ((unsigned)fp[(long)g1_[mh] * JJ + colB] << 16) | fp[(long)g0_[mh] * JJ + colB];
        }
        float4v a00 = {0.f, 0.f, 0.f, 0.f}, a01 = {0.f, 0.f, 0.f, 0.f};
        float4v a10 = {0.f, 0.f, 0.f, 0.f}, a11 = {0.f, 0.f, 0.f, 0.f};
#pragma unroll
        for (int kt = 0; kt < 10; ++kt) {
            const short8v b0 = buf[2 * kt], b1 = buf[2 * kt + 1];
            a00 = __builtin_amdgcn_mfma_f32_16x16x32_bf16(areg0[kt], b0, a00, 0, 0, 0);
            a10 = __builtin_amdgcn_mfma_f32_16x16x32_bf16(areg1[kt], b0, a10, 0, 0, 0);
            a01 = __builtin_amdgcn_mfma_f32_16x16x32_bf16(areg0[kt], b1, a01, 0, 0, 0);
            a11 = __builtin_amdgcn_mfma_f32_16x16x32_bf16(areg1[kt], b1, a11, 0, 0, 0);
        }
#pragma unroll
        for (int mh = 0; mh < 2; ++mh) {
            const unsigned floA = uA[mh] << 16, fhiA = uA[mh] & 0xffff0000u;
            const unsigned floB = uB[mh] << 16, fhiB = uB[mh] & 0xffff0000u;
#pragma unroll
            for (int reg = 0; reg < 4; ++reg) {
                const float fvA = __uint_as_float((floA & ~selm[mh][reg]) | (fhiA & selm[mh][reg]));
                const float aA = (mh == 0) ? a00[reg] : a10[reg];
                const float xA = fmaf(vmc[mh][reg], fvA, aA);
                const float eA = __expf(xA + xA);
                sp[mh][reg] = fmaf(wfA, __builtin_amdgcn_rcpf(eA + 1.f), sp[mh][reg]);
                const float fvB = __uint_as_float((floB & ~selm[mh][reg]) | (fhiB & selm[mh][reg]));
                const float aB = (mh == 0) ? a01[reg] : a11[reg];
                const float xB = fmaf(vmc[mh][reg], fvB, aB);
                const float eB = __expf(xB + xB);
                sp[mh][reg] = fmaf(wfB, __builtin_amdgcn_rcpf(eB + 1.f), sp[mh][reg]);
            }
        }
    };

    short8v bufA[20], bufB[20];
    loadB(bufA, 0);
#pragma unroll
    for (int nq = 0; nq < 8; ++nq) {
        const int npA = nq * 2;
        loadB(bufB, npA + 1);                    // in flight under compute(bufA)
        computeB(bufA, npA);
        if (npA + 2 < 16) loadB(bufA, npA + 2);  // in flight under compute(bufB)
        computeB(bufB, npA + 1);
    }

    // ---- reduce over 16 li lanes, direct store ----
    const float base = b_fc[0] + sumwf[0];
#pragma unroll
    for (int mh = 0; mh < 2; ++mh)
#pragma unroll
        for (int reg = 0; reg < 4; ++reg) {
            float v = sp[mh][reg];
            v += __shfl_xor(v, 1); v += __shfl_xor(v, 2);
            v += __shfl_xor(v, 4); v += __shfl_xor(v, 8);
            if (li == 0) scores[m0 + mh * 16 + lq * 4 + reg] = base - 2.f * v;
        }
}

// ---------------- kernel 3: softmax + mask + renorm + weighted sum -------------
__global__ __launch_bounds__(256) void k3_out(const float* __restrict__ scores,
                                              const float* __restrict__ nonzero,
                                              const float* __restrict__ embedded,
                                              float* __restrict__ out) {
    __shared__ float wgt[3][SS];
    const int b0 = blockIdx.x * 3;
    const int t = threadIdx.x;
    if (t < 3) {
        int b = b0 + t;
        if (b < BB) {
            float sc[SS], nz[SS];
            float mx = -1e30f;
            for (int s = 0; s < SS; ++s) {
                sc[s] = scores[b * SS + s];
                nz[s] = nonzero[b * SS + s];
                mx = fmaxf(mx, sc[s]);
            }
            float den = 0.f, e[SS];
            for (int s = 0; s < SS; ++s) { e[s] = nz[s] * __expf(sc[s] - mx); den += e[s]; }
            float inv = 1.f / den;
            for (int s = 0; s < SS; ++s) wgt[t][s] = e[s] * inv;
        }
    }
    __syncthreads();
    if (t < 225) {
        int r = t / 75, q = t - r * 75;
        int b = b0 + r;
        if (b < BB) {
            float4 a; a.x = a.y = a.z = a.w = 0.f;
#pragma unroll
            for (int s = 0; s < SS; ++s) {
                float4 e = *(const float4*)(embedded + ((long)b * SS + s) * DD + q * 4);
                float ww = wgt[r][s];
                a.x += ww * e.x; a.y += ww * e.y; a.z += ww * e.z; a.w += ww * e.w;
            }
            *(float4*)(out + (long)b * DD + q * 4) = a;
        }
    }
}

extern "C" void kernel_launch(void* const* d_in, const int* in_sizes, int n_in,
                              void* d_out, int out_size, void* d_ws, size_t ws_size,
                              hipStream_t stream) {
    const float* context  = (const float*)d_in[0];
    const float* embedded = (const float*)d_in[1];
    const int*   labels   = (const int*)d_in[2];
    const float* guide    = (const float*)d_in[3];
    const int*   ann      = (const int*)d_in[4];
    const float* W_sent   = (const float*)d_in[5];
    const float* b_sent   = (const float*)d_in[6];
    const float* W_emb    = (const float*)d_in[7];
    const float* b_emb    = (const float*)d_in[8];
    const float* w_fc     = (const float*)d_in[9];
    const float* b_fc     = (const float*)d_in[10];
    float* out = (float*)d_out;

    char* w = (char*)d_ws;
    __hip_bfloat16* femb = (__hip_bfloat16*)(w);               // 1024*512*2 = 1048576
    float* valid         = (float*)(w + 1048576);              // 655360
    float* nonzero       = (float*)(w + 1703936);              // 655360
    float* scores        = (float*)(w + 2359296);              // 655360
    __hip_bfloat16* Wt   = (__hip_bfloat16*)(w + 3014656);     // 40*512*8*2 = 327680
    __hip_bfloat16* Web  = (__hip_bfloat16*)(w + 3342336);     // 512*2112*2 = 2162688
    __hip_bfloat16* Gb   = (__hip_bfloat16*)(w + 5505024);     // 1000*2112*2= 4224000
    float* sums          = (float*)(w + 9729024);              // 4
    // total 9729028 bytes

    hipLaunchKernelGGL(kc_prep_wt, dim3((40 * 512 + 255) / 256), dim3(256), 0, stream,
                       W_sent, b_sent, b_emb, Wt);
    hipLaunchKernelGGL(kc_pad2, dim3((int)((1512L * 2112 + 255) / 256)), dim3(256), 0, stream,
                       W_emb, guide, Web, Gb);
    hipLaunchKernelGGL(kS_sumwf, dim3(1), dim3(512), 0, stream, w_fc, sums);
    hipLaunchKernelGGL(k0_valid, dim3(BB / 256), dim3(256), 0, stream,
                       labels, valid, nonzero);
    hipLaunchKernelGGL(k1_femb_mfma, dim3(16, JJ / 64), dim3(256), 0, stream,
                       Gb, Web, b_emb, femb);
    hipLaunchKernelGGL(k2_scores_mfma, dim3((BB * SS) / 128), dim3(256), 0, stream,
                       context, Wt, w_fc, b_fc, sums, femb, ann, valid, scores);
    hipLaunchKernelGGL(k3_out, dim3((BB + 2) / 3), dim3(256), 0, stream,
                       scores, nonzero, embedded, out);
}

// Round 16
// 439.109 us; speedup vs baseline: 2.1703x; 1.5969x over previous
//
#include <hip/hip_runtime.h>
#include <hip/hip_bf16.h>

#define BB 8192
#define SS 20
#define DD 300
#define JJ 512
#define NII 1000
#define VGG 2078
#define BP1 72           // k1 64x64 chunk lds row stride

typedef __attribute__((ext_vector_type(8))) short short8v;
typedef __attribute__((ext_vector_type(4))) float float4v;

__device__ __forceinline__ unsigned short bf16u(float x) {
    __hip_bfloat16 h = __float2bfloat16(x);
    return *(unsigned short*)&h;
}

// ---------------- combined pad+convert for W_emb (512 rows) + guide (1000 rows) -
__global__ __launch_bounds__(256) void kc_pad2(const float* __restrict__ W_emb,
                                               const float* __restrict__ guide,
                                               __hip_bfloat16* __restrict__ Web,
                                               __hip_bfloat16* __restrict__ Gb) {
    long idx = (long)blockIdx.x * 256 + threadIdx.x;
    if (idx >= 1512L * 2112) return;
    int r = (int)(idx / 2112), c = (int)(idx % 2112);
    if (r < JJ) {
        float v = (c < VGG) ? W_emb[(long)r * VGG + c] : 0.f;
        Web[(long)r * 2112 + c] = __float2bfloat16(v);
    } else {
        int g = r - JJ;
        float v = (c < VGG) ? guide[(long)g * VGG + c] : 0.f;
        Gb[(long)g * 2112 + c] = __float2bfloat16(v);
    }
}

// ---------------- Wt prep: B-fragment-transposed weights ----------------------
__global__ __launch_bounds__(256) void kc_prep_wt(const float* __restrict__ W_sent,
                                                  const float* __restrict__ b_sent,
                                                  const float* __restrict__ b_emb,
                                                  __hip_bfloat16* __restrict__ dst) {
    int idx = blockIdx.x * 256 + threadIdx.x;   // chunk id
    if (idx >= 40 * 512) return;
    int kb = idx >> 9, col = idx & 511;
#pragma unroll
    for (int e = 0; e < 8; ++e) {
        int k = kb * 8 + e;
        float v = (k < DD) ? W_sent[(long)col * DD + k]
                : (k == DD) ? b_sent[col]
                : (k == DD + 1) ? b_emb[col] : 0.f;
        dst[(long)idx * 8 + e] = __float2bfloat16(v);
    }
}

// ---------------- sum of w_fc (one block) --------------------------------------
__global__ __launch_bounds__(512) void kS_sumwf(const float* __restrict__ w_fc,
                                                float* __restrict__ out) {
    __shared__ float part[8];
    int t = threadIdx.x;
    float v = w_fc[t];
    v += __shfl_xor(v, 1);  v += __shfl_xor(v, 2);  v += __shfl_xor(v, 4);
    v += __shfl_xor(v, 8);  v += __shfl_xor(v, 16); v += __shfl_xor(v, 32);
    if ((t & 63) == 0) part[t >> 6] = v;
    __syncthreads();
    if (t == 0) {
        float s = 0.f;
#pragma unroll
        for (int i = 0; i < 8; ++i) s += part[i];
        out[0] = s;
    }
}

// ---------------- kernel 0: valid / nonzero masks ----------------
__global__ __launch_bounds__(256) void k0_valid(const int* __restrict__ labels,
                                                float* __restrict__ valid,
                                                float* __restrict__ nonzero) {
    int b = blockIdx.x * blockDim.x + threadIdx.x;
    if (b >= BB) return;
    float v = 1.f;
    for (int s = 0; s < SS; ++s) {
        float nz = (labels[b * SS + s] != 0) ? 1.f : 0.f;
        v *= nz;
        nonzero[b * SS + s] = nz;
        valid[b * SS + s] = v;
    }
}

// ---------------- kernel 1 (MFMA): femb = bf16(guide @ W_emb^T + b_emb) --------
__global__ __launch_bounds__(256) void k1_femb_mfma(
    const __hip_bfloat16* __restrict__ Gb,   // [NII][2112]
    const __hip_bfloat16* __restrict__ Web,  // [JJ][2112]
    const float* __restrict__ b_emb,
    __hip_bfloat16* __restrict__ femb) {     // [1024][JJ]
    __shared__ __hip_bfloat16 Al[64 * BP1];
    __shared__ __hip_bfloat16 Bl[64 * BP1];
    const int t = threadIdx.x;
    const int m0 = blockIdx.x * 64;
    const int n0 = blockIdx.y * 64;
    const int lane = t & 63;
    const int w = t >> 6;
    const int wm = w >> 1, wn = w & 1;
    const int li = lane & 15, lq = lane >> 4;

    float4v acc[2][2] = {};

    for (int kt = 0; kt < 33; ++kt) {
        for (int c = t; c < 512; c += 256) {
            int rr = c >> 3, off = (c & 7) * 8;
            int gr = m0 + rr; if (gr > NII - 1) gr = NII - 1;
            *(uint4*)&Al[rr * BP1 + off] =
                *(const uint4*)(Gb + (long)gr * 2112 + kt * 64 + off);
            *(uint4*)&Bl[rr * BP1 + off] =
                *(const uint4*)(Web + (long)(n0 + rr) * 2112 + kt * 64 + off);
        }
        __syncthreads();
#pragma unroll
        for (int ks = 0; ks < 2; ++ks) {
            short8v a[2], b[2];
#pragma unroll
            for (int mt = 0; mt < 2; ++mt)
                a[mt] = *(const short8v*)&Al[(wm * 32 + mt * 16 + li) * BP1 + ks * 32 + lq * 8];
#pragma unroll
            for (int nt = 0; nt < 2; ++nt)
                b[nt] = *(const short8v*)&Bl[(wn * 32 + nt * 16 + li) * BP1 + ks * 32 + lq * 8];
#pragma unroll
            for (int mt = 0; mt < 2; ++mt)
#pragma unroll
                for (int nt = 0; nt < 2; ++nt)
                    acc[mt][nt] = __builtin_amdgcn_mfma_f32_16x16x32_bf16(
                        a[mt], b[nt], acc[mt][nt], 0, 0, 0);
        }
        __syncthreads();
    }
#pragma unroll
    for (int nt = 0; nt < 2; ++nt) {
        int col = n0 + wn * 32 + nt * 16 + li;
        float be = b_emb[col];
#pragma unroll
        for (int mt = 0; mt < 2; ++mt)
#pragma unroll
            for (int reg = 0; reg < 4; ++reg) {
                int row = wm * 32 + mt * 16 + lq * 4 + reg;
                femb[(long)(m0 + row) * JJ + col] = __float2bfloat16(acc[mt][nt][reg] + be);
            }
    }
}

// ---------------- kernel 2 (MFMA): fused scores — round-12 structure + T5 -----
// 256 threads = 4 waves; block owns 64 m-rows (wave: 16). Wave sweeps all 512
// j-cols in 16 np-steps. Epilogue operands (femb pairs, w_fc) preloaded into
// registers; loop body's only memory ops are the 20 B-frag loads per tile,
// 2-deep software pipeline with named buffers. 124 VGPR, no spill (round 12:
// 182us — session-best k2). Added: s_setprio around the MFMA cluster (T5) —
// these waves are free-running (no barriers), the regime where setprio helps.
// Register budget lesson (r9/10/13/14/15): this toolchain hard-caps at 128
// arch-VGPRs and SPILLS to reach it; designs must fit ~125 VGPR.
__global__ __launch_bounds__(256)
__attribute__((amdgpu_waves_per_eu(2, 4)))
void k2_scores_mfma(
    const float* __restrict__ context,
    const __hip_bfloat16* __restrict__ Wt,   // frag-transposed [40*512] chunks
    const float* __restrict__ w_fc,
    const float* __restrict__ b_fc,
    const float* __restrict__ sumwf,
    const __hip_bfloat16* __restrict__ femb, // [1024][JJ]
    const int* __restrict__ ann,
    const float* __restrict__ valid,
    float* __restrict__ scores) {
    const int t = threadIdx.x;
    const int wid = t >> 6, lane = t & 63;
    const int li = lane & 15, lq = lane >> 4;
    const int m0 = blockIdx.x * 64 + wid * 16;

    // ---- C-row metadata ----
    const int mslot = m0 + lq * 4;
    const int b0r = mslot / SS;
    const int b3r = (mslot + 3) / SS;
    const int g0 = ann[2 * b0r];
    const int g1 = ann[2 * b3r];
    float vmc[4]; unsigned selm[4];
#pragma unroll
    for (int reg = 0; reg < 4; ++reg) {
        vmc[reg] = valid[mslot + reg];
        selm[reg] = (((mslot + reg) / SS) != b0r) ? 0xffffffffu : 0u;
    }

    // ---- preload ALL per-np epilogue operands into registers ----
    const unsigned short* fp = (const unsigned short*)femb;
    unsigned fA[16], fB[16], wpk[16];
#pragma unroll
    for (int np = 0; np < 16; ++np) {
        const int colA = np * 32 + li;
        const int colB = colA + 16;
        fA[np] = ((unsigned)fp[(long)g1 * JJ + colA] << 16) | fp[(long)g0 * JJ + colA];
        fB[np] = ((unsigned)fp[(long)g1 * JJ + colB] << 16) | fp[(long)g0 * JJ + colB];
        wpk[np] = ((unsigned)bf16u(w_fc[colB]) << 16) | bf16u(w_fc[colA]);
    }

    // ---- A fragments (row = li), f32 -> bf16 in regs; bias cols at k300/301 --
    const float* crow = context + (long)(m0 + li) * DD;
    const float vA = valid[m0 + li];
    short8v areg[10];
#pragma unroll
    for (int kt = 0; kt < 9; ++kt) {
        const int k0 = kt * 32 + lq * 8;
        float4 u = *(const float4*)(crow + k0);
        float4 v2 = *(const float4*)(crow + k0 + 4);
        short8v a;
        a[0] = (short)bf16u(u.x);  a[1] = (short)bf16u(u.y);
        a[2] = (short)bf16u(u.z);  a[3] = (short)bf16u(u.w);
        a[4] = (short)bf16u(v2.x); a[5] = (short)bf16u(v2.y);
        a[6] = (short)bf16u(v2.z); a[7] = (short)bf16u(v2.w);
        areg[kt] = a;
    }
    {   // kt=9: k 288..319, col300=1.0, col301=1-valid, rest 0
        short8v a = {0, 0, 0, 0, 0, 0, 0, 0};
        if (lq == 0) {
            float4 u = *(const float4*)(crow + 288);
            float4 v2 = *(const float4*)(crow + 292);
            a[0] = (short)bf16u(u.x);  a[1] = (short)bf16u(u.y);
            a[2] = (short)bf16u(u.z);  a[3] = (short)bf16u(u.w);
            a[4] = (short)bf16u(v2.x); a[5] = (short)bf16u(v2.y);
            a[6] = (short)bf16u(v2.z); a[7] = (short)bf16u(v2.w);
        } else if (lq == 1) {
            float4 u = *(const float4*)(crow + 296);
            a[0] = (short)bf16u(u.x);  a[1] = (short)bf16u(u.y);
            a[2] = (short)bf16u(u.z);  a[3] = (short)bf16u(u.w);
            a[4] = (short)bf16u(1.f);  a[5] = (short)bf16u(1.f - vA);
        }
        areg[9] = a;
    }

    const __hip_bfloat16* pb = Wt + ((long)lq * 512 + li) * 8;
    float sp[4] = {0.f, 0.f, 0.f, 0.f};

    auto loadB = [&](short8v (&buf)[20], int np) {
        const __hip_bfloat16* pn = pb + (long)np * 256;
#pragma unroll
        for (int kt = 0; kt < 10; ++kt) {
            buf[2 * kt]     = *(const short8v*)(pn + (long)kt * 16384);
            buf[2 * kt + 1] = *(const short8v*)(pn + (long)kt * 16384 + 128);
        }
    };
    // pure-register tile compute: 20 MFMA + epilogue (NO memory ops)
    auto computeB = [&](short8v (&buf)[20], unsigned uA, unsigned uB, unsigned wp) {
        float4v a0 = {0.f, 0.f, 0.f, 0.f}, a1 = {0.f, 0.f, 0.f, 0.f};
        __builtin_amdgcn_s_setprio(1);
#pragma unroll
        for (int kt = 0; kt < 10; ++kt) {
            a0 = __builtin_amdgcn_mfma_f32_16x16x32_bf16(areg[kt], buf[2 * kt], a0, 0, 0, 0);
            a1 = __builtin_amdgcn_mfma_f32_16x16x32_bf16(areg[kt], buf[2 * kt + 1], a1, 0, 0, 0);
        }
        __builtin_amdgcn_s_setprio(0);
        const float wfA = __uint_as_float(wp << 16);
        const float wfB = __uint_as_float(wp & 0xffff0000u);
        const unsigned floA = uA << 16, fhiA = uA & 0xffff0000u;
        const unsigned floB = uB << 16, fhiB = uB & 0xffff0000u;
#pragma unroll
        for (int reg = 0; reg < 4; ++reg) {
            const float fvA = __uint_as_float((floA & ~selm[reg]) | (fhiA & selm[reg]));
            const float xA = fmaf(vmc[reg], fvA, a0[reg]);
            const float eA = __expf(xA + xA);
            sp[reg] = fmaf(wfA, __builtin_amdgcn_rcpf(eA + 1.f), sp[reg]);
            const float fvB = __uint_as_float((floB & ~selm[reg]) | (fhiB & selm[reg]));
            const float xB = fmaf(vmc[reg], fvB, a1[reg]);
            const float eB = __expf(xB + xB);
            sp[reg] = fmaf(wfB, __builtin_amdgcn_rcpf(eB + 1.f), sp[reg]);
        }
    };

    short8v bufA[20], bufB[20];
    loadB(bufA, 0);
#pragma unroll
    for (int nq = 0; nq < 8; ++nq) {
        const int npA = nq * 2;
        loadB(bufB, npA + 1);                       // in flight under compute(bufA)
        computeB(bufA, fA[npA], fB[npA], wpk[npA]);
        if (npA + 2 < 16) loadB(bufA, npA + 2);     // in flight under compute(bufB)
        computeB(bufB, fA[npA + 1], fB[npA + 1], wpk[npA + 1]);
    }

    // ---- reduce over 16 li lanes, direct store ----
    const float base = b_fc[0] + sumwf[0];
#pragma unroll
    for (int reg = 0; reg < 4; ++reg) {
        float v = sp[reg];
        v += __shfl_xor(v, 1); v += __shfl_xor(v, 2);
        v += __shfl_xor(v, 4); v += __shfl_xor(v, 8);
        if (li == 0) scores[mslot + reg] = base - 2.f * v;
    }
}

// ---------------- kernel 3: softmax + mask + renorm + weighted sum -------------
__global__ __launch_bounds__(256) void k3_out(const float* __restrict__ scores,
                                              const float* __restrict__ nonzero,
                                              const float* __restrict__ embedded,
                                              float* __restrict__ out) {
    __shared__ float wgt[3][SS];
    const int b0 = blockIdx.x * 3;
    const int t = threadIdx.x;
    if (t < 3) {
        int b = b0 + t;
        if (b < BB) {
            float sc[SS], nz[SS];
            float mx = -1e30f;
            for (int s = 0; s < SS; ++s) {
                sc[s] = scores[b * SS + s];
                nz[s] = nonzero[b * SS + s];
                mx = fmaxf(mx, sc[s]);
            }
            float den = 0.f, e[SS];
            for (int s = 0; s < SS; ++s) { e[s] = nz[s] * __expf(sc[s] - mx); den += e[s]; }
            float inv = 1.f / den;
            for (int s = 0; s < SS; ++s) wgt[t][s] = e[s] * inv;
        }
    }
    __syncthreads();
    if (t < 225) {
        int r = t / 75, q = t - r * 75;
        int b = b0 + r;
        if (b < BB) {
            float4 a; a.x = a.y = a.z = a.w = 0.f;
#pragma unroll
            for (int s = 0; s < SS; ++s) {
                float4 e = *(const float4*)(embedded + ((long)b * SS + s) * DD + q * 4);
                float ww = wgt[r][s];
                a.x += ww * e.x; a.y += ww * e.y; a.z += ww * e.z; a.w += ww * e.w;
            }
            *(float4*)(out + (long)b * DD + q * 4) = a;
        }
    }
}

extern "C" void kernel_launch(void* const* d_in, const int* in_sizes, int n_in,
                              void* d_out, int out_size, void* d_ws, size_t ws_size,
                              hipStream_t stream) {
    const float* context  = (const float*)d_in[0];
    const float* embedded = (const float*)d_in[1];
    const int*   labels   = (const int*)d_in[2];
    const float* guide    = (const float*)d_in[3];
    const int*   ann      = (const int*)d_in[4];
    const float* W_sent   = (const float*)d_in[5];
    const float* b_sent   = (const float*)d_in[6];
    const float* W_emb    = (const float*)d_in[7];
    const float* b_emb    = (const float*)d_in[8];
    const float* w_fc     = (const float*)d_in[9];
    const float* b_fc     = (const float*)d_in[10];
    float* out = (float*)d_out;

    char* w = (char*)d_ws;
    __hip_bfloat16* femb = (__hip_bfloat16*)(w);               // 1024*512*2 = 1048576
    float* valid         = (float*)(w + 1048576);              // 655360
    float* nonzero       = (float*)(w + 1703936);              // 655360
    float* scores        = (float*)(w + 2359296);              // 655360
    __hip_bfloat16* Wt   = (__hip_bfloat16*)(w + 3014656);     // 40*512*8*2 = 327680
    __hip_bfloat16* Web  = (__hip_bfloat16*)(w + 3342336);     // 512*2112*2 = 2162688
    __hip_bfloat16* Gb   = (__hip_bfloat16*)(w + 5505024);     // 1000*2112*2= 4224000
    float* sums          = (float*)(w + 9729024);              // 4
    // total 9729028 bytes

    hipLaunchKernelGGL(kc_prep_wt, dim3((40 * 512 + 255) / 256), dim3(256), 0, stream,
                       W_sent, b_sent, b_emb, Wt);
    hipLaunchKernelGGL(kc_pad2, dim3((int)((1512L * 2112 + 255) / 256)), dim3(256), 0, stream,
                       W_emb, guide, Web, Gb);
    hipLaunchKernelGGL(kS_sumwf, dim3(1), dim3(512), 0, stream, w_fc, sums);
    hipLaunchKernelGGL(k0_valid, dim3(BB / 256), dim3(256), 0, stream,
                       labels, valid, nonzero);
    hipLaunchKernelGGL(k1_femb_mfma, dim3(16, JJ / 64), dim3(256), 0, stream,
                       Gb, Web, b_emb, femb);
    hipLaunchKernelGGL(k2_scores_mfma, dim3((BB * SS) / 64), dim3(256), 0, stream,
                       context, Wt, w_fc, b_fc, sums, femb, ann, valid, scores);
    hipLaunchKernelGGL(k3_out, dim3((BB + 2) / 3), dim3(256), 0, stream,
                       scores, nonzero, embedded, out);
}

// Round 17
// 238.359 us; speedup vs baseline: 3.9982x; 1.8422x over previous
//
#include <hip/hip_runtime.h>
#include <hip/hip_bf16.h>

#define BB 8192
#define SS 20
#define DD 300
#define JJ 512
#define NII 1000
#define VGG 2078
#define BP1 72           // k1 64x64 chunk lds row stride

typedef __attribute__((ext_vector_type(8))) short short8v;
typedef __attribute__((ext_vector_type(4))) float float4v;

__device__ __forceinline__ unsigned short bf16u(float x) {
    __hip_bfloat16 h = __float2bfloat16(x);
    return *(unsigned short*)&h;
}

// ---------------- combined pad+convert for W_emb (512 rows) + guide (1000 rows) -
__global__ __launch_bounds__(256) void kc_pad2(const float* __restrict__ W_emb,
                                               const float* __restrict__ guide,
                                               __hip_bfloat16* __restrict__ Web,
                                               __hip_bfloat16* __restrict__ Gb) {
    long idx = (long)blockIdx.x * 256 + threadIdx.x;
    if (idx >= 1512L * 2112) return;
    int r = (int)(idx / 2112), c = (int)(idx % 2112);
    if (r < JJ) {
        float v = (c < VGG) ? W_emb[(long)r * VGG + c] : 0.f;
        Web[(long)r * 2112 + c] = __float2bfloat16(v);
    } else {
        int g = r - JJ;
        float v = (c < VGG) ? guide[(long)g * VGG + c] : 0.f;
        Gb[(long)g * 2112 + c] = __float2bfloat16(v);
    }
}

// ---------------- Wt prep: B-fragment-transposed weights ----------------------
// Wt chunk (kb, col), kb = k/8 in [0,40), col in [0,512): 8 bf16 of
// W'[col][kb*8..kb*8+8), W'[col] = [W_sent row | b_sent | b_emb | 0..].
__global__ __launch_bounds__(256) void kc_prep_wt(const float* __restrict__ W_sent,
                                                  const float* __restrict__ b_sent,
                                                  const float* __restrict__ b_emb,
                                                  __hip_bfloat16* __restrict__ dst) {
    int idx = blockIdx.x * 256 + threadIdx.x;   // chunk id
    if (idx >= 40 * 512) return;
    int kb = idx >> 9, col = idx & 511;
#pragma unroll
    for (int e = 0; e < 8; ++e) {
        int k = kb * 8 + e;
        float v = (k < DD) ? W_sent[(long)col * DD + k]
                : (k == DD) ? b_sent[col]
                : (k == DD + 1) ? b_emb[col] : 0.f;
        dst[(long)idx * 8 + e] = __float2bfloat16(v);
    }
}

// ---------------- sum of w_fc (one block) --------------------------------------
__global__ __launch_bounds__(512) void kS_sumwf(const float* __restrict__ w_fc,
                                                float* __restrict__ out) {
    __shared__ float part[8];
    int t = threadIdx.x;
    float v = w_fc[t];
    v += __shfl_xor(v, 1);  v += __shfl_xor(v, 2);  v += __shfl_xor(v, 4);
    v += __shfl_xor(v, 8);  v += __shfl_xor(v, 16); v += __shfl_xor(v, 32);
    if ((t & 63) == 0) part[t >> 6] = v;
    __syncthreads();
    if (t == 0) {
        float s = 0.f;
#pragma unroll
        for (int i = 0; i < 8; ++i) s += part[i];
        out[0] = s;
    }
}

// ---------------- kernel 0: valid / nonzero masks ----------------
__global__ __launch_bounds__(256) void k0_valid(const int* __restrict__ labels,
                                                float* __restrict__ valid,
                                                float* __restrict__ nonzero) {
    int b = blockIdx.x * blockDim.x + threadIdx.x;
    if (b >= BB) return;
    float v = 1.f;
    for (int s = 0; s < SS; ++s) {
        float nz = (labels[b * SS + s] != 0) ? 1.f : 0.f;
        v *= nz;
        nonzero[b * SS + s] = nz;
        valid[b * SS + s] = v;
    }
}

// ---------------- kernel 1 (MFMA): femb = bf16(guide @ W_emb^T + b_emb) --------
__global__ __launch_bounds__(256) void k1_femb_mfma(
    const __hip_bfloat16* __restrict__ Gb,   // [NII][2112]
    const __hip_bfloat16* __restrict__ Web,  // [JJ][2112]
    const float* __restrict__ b_emb,
    __hip_bfloat16* __restrict__ femb) {     // [1024][JJ]
    __shared__ __hip_bfloat16 Al[64 * BP1];
    __shared__ __hip_bfloat16 Bl[64 * BP1];
    const int t = threadIdx.x;
    const int m0 = blockIdx.x * 64;
    const int n0 = blockIdx.y * 64;
    const int lane = t & 63;
    const int w = t >> 6;
    const int wm = w >> 1, wn = w & 1;
    const int li = lane & 15, lq = lane >> 4;

    float4v acc[2][2] = {};

    for (int kt = 0; kt < 33; ++kt) {
        for (int c = t; c < 512; c += 256) {
            int rr = c >> 3, off = (c & 7) * 8;
            int gr = m0 + rr; if (gr > NII - 1) gr = NII - 1;
            *(uint4*)&Al[rr * BP1 + off] =
                *(const uint4*)(Gb + (long)gr * 2112 + kt * 64 + off);
            *(uint4*)&Bl[rr * BP1 + off] =
                *(const uint4*)(Web + (long)(n0 + rr) * 2112 + kt * 64 + off);
        }
        __syncthreads();
#pragma unroll
        for (int ks = 0; ks < 2; ++ks) {
            short8v a[2], b[2];
#pragma unroll
            for (int mt = 0; mt < 2; ++mt)
                a[mt] = *(const short8v*)&Al[(wm * 32 + mt * 16 + li) * BP1 + ks * 32 + lq * 8];
#pragma unroll
            for (int nt = 0; nt < 2; ++nt)
                b[nt] = *(const short8v*)&Bl[(wn * 32 + nt * 16 + li) * BP1 + ks * 32 + lq * 8];
#pragma unroll
            for (int mt = 0; mt < 2; ++mt)
#pragma unroll
                for (int nt = 0; nt < 2; ++nt)
                    acc[mt][nt] = __builtin_amdgcn_mfma_f32_16x16x32_bf16(
                        a[mt], b[nt], acc[mt][nt], 0, 0, 0);
        }
        __syncthreads();
    }
#pragma unroll
    for (int nt = 0; nt < 2; ++nt) {
        int col = n0 + wn * 32 + nt * 16 + li;
        float be = b_emb[col];
#pragma unroll
        for (int mt = 0; mt < 2; ++mt)
#pragma unroll
            for (int reg = 0; reg < 4; ++reg) {
                int row = wm * 32 + mt * 16 + lq * 4 + reg;
                femb[(long)(m0 + row) * JJ + col] = __float2bfloat16(acc[mt][nt][reg] + be);
            }
    }
}

// ---------------- kernel 2 (MFMA): fused scores — zero LDS, pipelined B -------
// EXACT round-12 configuration (session best: k2 182us, VGPR 124, no spill).
// 256 threads = 4 waves; block owns 64 m-rows (wave: 16). Wave sweeps all 512
// j-cols in 16 np-steps. A resident in areg[10]; B streamed coalesced from
// fragment-transposed Wt (L2-resident) through a 2-deep software pipeline with
// two named 20-frag register buffers. Per-np femb/w_fc loads stay IN the loop:
// hoisting them (r13) or adding setprio (r16) pushes the live set past the
// toolchain's hard 128-VGPR cap and spills (157-280MB scratch). Do not modify
// without watching VGPR_Count + WRITE_SIZE.
__global__ __launch_bounds__(256)
__attribute__((amdgpu_waves_per_eu(2, 4)))
void k2_scores_mfma(
    const float* __restrict__ context,
    const __hip_bfloat16* __restrict__ Wt,   // frag-transposed [40*512] chunks
    const float* __restrict__ w_fc,
    const float* __restrict__ b_fc,
    const float* __restrict__ sumwf,
    const __hip_bfloat16* __restrict__ femb, // [1024][JJ]
    const int* __restrict__ ann,
    const float* __restrict__ valid,
    float* __restrict__ scores) {
    const int t = threadIdx.x;
    const int wid = t >> 6, lane = t & 63;
    const int li = lane & 15, lq = lane >> 4;
    const int m0 = blockIdx.x * 64 + wid * 16;

    // ---- A fragments (row = li), f32 -> bf16 in regs; bias cols at k300/301 --
    const float* crow = context + (long)(m0 + li) * DD;
    const float vA = valid[m0 + li];
    short8v areg[10];
#pragma unroll
    for (int kt = 0; kt < 9; ++kt) {
        const int k0 = kt * 32 + lq * 8;
        float4 u = *(const float4*)(crow + k0);
        float4 v2 = *(const float4*)(crow + k0 + 4);
        short8v a;
        a[0] = (short)bf16u(u.x);  a[1] = (short)bf16u(u.y);
        a[2] = (short)bf16u(u.z);  a[3] = (short)bf16u(u.w);
        a[4] = (short)bf16u(v2.x); a[5] = (short)bf16u(v2.y);
        a[6] = (short)bf16u(v2.z); a[7] = (short)bf16u(v2.w);
        areg[kt] = a;
    }
    {   // kt=9: k 288..319, col300=1.0, col301=1-valid, rest 0
        short8v a = {0, 0, 0, 0, 0, 0, 0, 0};
        if (lq == 0) {
            float4 u = *(const float4*)(crow + 288);
            float4 v2 = *(const float4*)(crow + 292);
            a[0] = (short)bf16u(u.x);  a[1] = (short)bf16u(u.y);
            a[2] = (short)bf16u(u.z);  a[3] = (short)bf16u(u.w);
            a[4] = (short)bf16u(v2.x); a[5] = (short)bf16u(v2.y);
            a[6] = (short)bf16u(v2.z); a[7] = (short)bf16u(v2.w);
        } else if (lq == 1) {
            float4 u = *(const float4*)(crow + 296);
            a[0] = (short)bf16u(u.x);  a[1] = (short)bf16u(u.y);
            a[2] = (short)bf16u(u.z);  a[3] = (short)bf16u(u.w);
            a[4] = (short)bf16u(1.f);  a[5] = (short)bf16u(1.f - vA);
        }
        areg[9] = a;
    }

    // ---- C-row metadata (rows = mslot..mslot+3) ----
    const int mslot = m0 + lq * 4;
    const int b0r = mslot / SS;
    const int b3r = (mslot + 3) / SS;
    const int g0 = ann[2 * b0r];
    const int g1 = ann[2 * b3r];
    float vmc[4]; unsigned selm[4];
#pragma unroll
    for (int reg = 0; reg < 4; ++reg) {
        vmc[reg] = valid[mslot + reg];
        selm[reg] = (((mslot + reg) / SS) != b0r) ? 0xffffffffu : 0u;
    }
    const unsigned short* fp = (const unsigned short*)femb;
    const __hip_bfloat16* pb = Wt + ((long)lq * 512 + li) * 8;

    float sp[4] = {0.f, 0.f, 0.f, 0.f};

    // load all 20 B-frags of tile np into a named register buffer
    auto loadB = [&](short8v (&buf)[20], int np) {
        const __hip_bfloat16* pn = pb + (long)np * 256;
#pragma unroll
        for (int kt = 0; kt < 10; ++kt) {
            buf[2 * kt]     = *(const short8v*)(pn + (long)kt * 16384);
            buf[2 * kt + 1] = *(const short8v*)(pn + (long)kt * 16384 + 128);
        }
    };
    // 20 MFMAs + fused epilogue for tile np from a named buffer
    auto computeB = [&](short8v (&buf)[20], int np) {
        const int colA = np * 32 + li;
        const int colB = colA + 16;
        const unsigned uA = ((unsigned)fp[(long)g1 * JJ + colA] << 16) | fp[(long)g0 * JJ + colA];
        const unsigned uB = ((unsigned)fp[(long)g1 * JJ + colB] << 16) | fp[(long)g0 * JJ + colB];
        const float wfA = w_fc[colA];
        const float wfB = w_fc[colB];
        float4v a0 = {0.f, 0.f, 0.f, 0.f}, a1 = {0.f, 0.f, 0.f, 0.f};
#pragma unroll
        for (int kt = 0; kt < 10; ++kt) {
            a0 = __builtin_amdgcn_mfma_f32_16x16x32_bf16(areg[kt], buf[2 * kt], a0, 0, 0, 0);
            a1 = __builtin_amdgcn_mfma_f32_16x16x32_bf16(areg[kt], buf[2 * kt + 1], a1, 0, 0, 0);
        }
        const unsigned floA = uA << 16, fhiA = uA & 0xffff0000u;
        const unsigned floB = uB << 16, fhiB = uB & 0xffff0000u;
#pragma unroll
        for (int reg = 0; reg < 4; ++reg) {
            const float fvA = __uint_as_float((floA & ~selm[reg]) | (fhiA & selm[reg]));
            const float xA = fmaf(vmc[reg], fvA, a0[reg]);
            const float eA = __expf(xA + xA);
            sp[reg] = fmaf(wfA, __builtin_amdgcn_rcpf(eA + 1.f), sp[reg]);
            const float fvB = __uint_as_float((floB & ~selm[reg]) | (fhiB & selm[reg]));
            const float xB = fmaf(vmc[reg], fvB, a1[reg]);
            const float eB = __expf(xB + xB);
            sp[reg] = fmaf(wfB, __builtin_amdgcn_rcpf(eB + 1.f), sp[reg]);
        }
    };

    short8v bufA[20], bufB[20];
    loadB(bufA, 0);
    for (int nq = 0; nq < 8; ++nq) {
        const int npA = nq * 2;
        loadB(bufB, npA + 1);            // in flight under computeB(bufA)
        computeB(bufA, npA);
        if (npA + 2 < 16) loadB(bufA, npA + 2);  // in flight under computeB(bufB)
        computeB(bufB, npA + 1);
    }

    // ---- reduce over 16 li lanes, direct store ----
    const float base = b_fc[0] + sumwf[0];
#pragma unroll
    for (int reg = 0; reg < 4; ++reg) {
        float v = sp[reg];
        v += __shfl_xor(v, 1); v += __shfl_xor(v, 2);
        v += __shfl_xor(v, 4); v += __shfl_xor(v, 8);
        if (li == 0) scores[mslot + reg] = base - 2.f * v;
    }
}

// ---------------- kernel 3: softmax + mask + renorm + weighted sum -------------
__global__ __launch_bounds__(256) void k3_out(const float* __restrict__ scores,
                                              const float* __restrict__ nonzero,
                                              const float* __restrict__ embedded,
                                              float* __restrict__ out) {
    __shared__ float wgt[3][SS];
    const int b0 = blockIdx.x * 3;
    const int t = threadIdx.x;
    if (t < 3) {
        int b = b0 + t;
        if (b < BB) {
            float sc[SS], nz[SS];
            float mx = -1e30f;
            for (int s = 0; s < SS; ++s) {
                sc[s] = scores[b * SS + s];
                nz[s] = nonzero[b * SS + s];
                mx = fmaxf(mx, sc[s]);
            }
            float den = 0.f, e[SS];
            for (int s = 0; s < SS; ++s) { e[s] = nz[s] * __expf(sc[s] - mx); den += e[s]; }
            float inv = 1.f / den;
            for (int s = 0; s < SS; ++s) wgt[t][s] = e[s] * inv;
        }
    }
    __syncthreads();
    if (t < 225) {
        int r = t / 75, q = t - r * 75;
        int b = b0 + r;
        if (b < BB) {
            float4 a; a.x = a.y = a.z = a.w = 0.f;
#pragma unroll
            for (int s = 0; s < SS; ++s) {
                float4 e = *(const float4*)(embedded + ((long)b * SS + s) * DD + q * 4);
                float ww = wgt[r][s];
                a.x += ww * e.x; a.y += ww * e.y; a.z += ww * e.z; a.w += ww * e.w;
            }
            *(float4*)(out + (long)b * DD + q * 4) = a;
        }
    }
}

extern "C" void kernel_launch(void* const* d_in, const int* in_sizes, int n_in,
                              void* d_out, int out_size, void* d_ws, size_t ws_size,
                              hipStream_t stream) {
    const float* context  = (const float*)d_in[0];
    const float* embedded = (const float*)d_in[1];
    const int*   labels   = (const int*)d_in[2];
    const float* guide    = (const float*)d_in[3];
    const int*   ann      = (const int*)d_in[4];
    const float* W_sent   = (const float*)d_in[5];
    const float* b_sent   = (const float*)d_in[6];
    const float* W_emb    = (const float*)d_in[7];
    const float* b_emb    = (const float*)d_in[8];
    const float* w_fc     = (const float*)d_in[9];
    const float* b_fc     = (const float*)d_in[10];
    float* out = (float*)d_out;

    char* w = (char*)d_ws;
    __hip_bfloat16* femb = (__hip_bfloat16*)(w);               // 1024*512*2 = 1048576
    float* valid         = (float*)(w + 1048576);              // 655360
    float* nonzero       = (float*)(w + 1703936);              // 655360
    float* scores        = (float*)(w + 2359296);              // 655360
    __hip_bfloat16* Wt   = (__hip_bfloat16*)(w + 3014656);     // 40*512*8*2 = 327680
    __hip_bfloat16* Web  = (__hip_bfloat16*)(w + 3342336);     // 512*2112*2 = 2162688
    __hip_bfloat16* Gb   = (__hip_bfloat16*)(w + 5505024);     // 1000*2112*2= 4224000
    float* sums          = (float*)(w + 9729024);              // 4
    // total 9729028 bytes

    hipLaunchKernelGGL(kc_prep_wt, dim3((40 * 512 + 255) / 256), dim3(256), 0, stream,
                       W_sent, b_sent, b_emb, Wt);
    hipLaunchKernelGGL(kc_pad2, dim3((int)((1512L * 2112 + 255) / 256)), dim3(256), 0, stream,
                       W_emb, guide, Web, Gb);
    hipLaunchKernelGGL(kS_sumwf, dim3(1), dim3(512), 0, stream, w_fc, sums);
    hipLaunchKernelGGL(k0_valid, dim3(BB / 256), dim3(256), 0, stream,
                       labels, valid, nonzero);
    hipLaunchKernelGGL(k1_femb_mfma, dim3(16, JJ / 64), dim3(256), 0, stream,
                       Gb, Web, b_emb, femb);
    hipLaunchKernelGGL(k2_scores_mfma, dim3((BB * SS) / 64), dim3(256), 0, stream,
                       context, Wt, w_fc, b_fc, sums, femb, ann, valid, scores);
    hipLaunchKernelGGL(k3_out, dim3((BB + 2) / 3), dim3(256), 0, stream,
                       scores, nonzero, embedded, out);
}